// Round 10
// baseline (317.361 us; speedup 1.0000x reference)
//
#include <hip/hip_runtime.h>
#include <hip/hip_bf16.h>
#include <math.h>

// Problem constants (B,T,D,N from the reference)
#define BB 4
#define TT 1024
#define DD 1024
#define NNs 16
#define MM (BB*TT)          // 4096 rows
#define MMDD ((size_t)MM*DD)
#define CHUNK 64
#define NCHUNK (TT/CHUNK)   // 16

typedef short bf16x8 __attribute__((ext_vector_type(8)));
typedef float f32x4  __attribute__((ext_vector_type(4)));

__device__ __forceinline__ float silu_f(float v)     { return v / (1.f + __expf(-v)); }
__device__ __forceinline__ float softplus_f(float v) { return fmaxf(v, 0.f) + log1pf(__expf(-fabsf(v))); }

// fp32 -> bf16 (RNE) as raw bits
__device__ __forceinline__ unsigned short f2bf(float f) {
  unsigned u = __builtin_bit_cast(unsigned, f);
  u += 0x7fffu + ((u >> 16) & 1u);
  return (unsigned short)(u >> 16);
}
__device__ __forceinline__ unsigned pk2(float a, float b) {
  return (unsigned)f2bf(a) | ((unsigned)f2bf(b) << 16);
}

// async global->LDS, 16B per lane; lds ptr must be wave-uniform
__device__ __forceinline__ void gload16(const void* g, void* l) {
  __builtin_amdgcn_global_load_lds(
      (const __attribute__((address_space(1))) unsigned*)g,
      (__attribute__((address_space(3))) unsigned*)l, 16, 0, 0);
}

// T1: bijective chunked XCD swizzle (m204).
__device__ __forceinline__ int2 xcd_swz(int gx) {
  int nwg  = gx * (int)gridDim.y;
  int orig = (int)blockIdx.y * gx + (int)blockIdx.x;
  int q = nwg >> 3, r = nwg & 7;
  int xcd = orig & 7, i = orig >> 3;
  int wg = (xcd < r ? xcd * (q + 1) : r * (q + 1) + (xcd - r) * q) + i;
  return make_int2(wg % gx, wg / gx);
}

// ---------------------------------------------------------------------------
// Weight convert+transpose x4: W[K][N] f32 -> Wt[N][K] bf16 (K=N=DD), z-batched
// ---------------------------------------------------------------------------
__global__ __launch_bounds__(256) void wconv_t4(
    const float* __restrict__ W0, const float* __restrict__ W1,
    const float* __restrict__ W2, const float* __restrict__ W3,
    short* __restrict__ o0, short* __restrict__ o1,
    short* __restrict__ o2, short* __restrict__ o3)
{
  const float* W; short* Wt;
  switch (blockIdx.z) {
    case 0:  W = W0; Wt = o0; break;
    case 1:  W = W1; Wt = o1; break;
    case 2:  W = W2; Wt = o2; break;
    default: W = W3; Wt = o3; break;
  }
  __shared__ float t[32][33];
  int n0 = blockIdx.x * 32, k0 = blockIdx.y * 32;
  int r  = threadIdx.x >> 3;
  int c4 = (threadIdx.x & 7) * 4;
  float4 v = *(const float4*)(W + (size_t)(k0 + r) * DD + n0 + c4);
  t[r][c4+0] = v.x; t[r][c4+1] = v.y; t[r][c4+2] = v.z; t[r][c4+3] = v.w;
  __syncthreads();
  short q0 = (short)f2bf(t[c4+0][r]);
  short q1 = (short)f2bf(t[c4+1][r]);
  short q2 = (short)f2bf(t[c4+2][r]);
  short q3 = (short)f2bf(t[c4+3][r]);
  *(short4*)(Wt + (size_t)(n0 + r) * DD + k0 + c4) = make_short4(q0, q1, q2, q3);
}

// Wb[D][16], Wc[D][16] f32 -> Wbct[32][D] bf16 (rows 0-15 = Wb^T, 16-31 = Wc^T)
__global__ __launch_bounds__(256) void wbc_t(
    const float* __restrict__ Wb, const float* __restrict__ Wc,
    short* __restrict__ Wbct)
{
  int idx = blockIdx.x * 256 + threadIdx.x;  // 32*1024 = 32768
  int k = idx & (DD - 1);
  int n = idx >> 10;
  const float* W = (n < 16) ? Wb : Wc;
  Wbct[(size_t)n * DD + k] = (short)f2bf(W[(size_t)k * NNs + (n & 15)]);
}

// fp32 -> bf16 bulk convert (8 elems/thread)
__global__ __launch_bounds__(256) void to_bf16(
    const float* __restrict__ in, short* __restrict__ out)
{
  size_t i = (size_t)(blockIdx.x * 256 + threadIdx.x) * 8;
  float4 a = *(const float4*)(in + i);
  float4 b = *(const float4*)(in + i + 4);
  *(uint4*)(out + i) = make_uint4(pk2(a.x,a.y), pk2(a.z,a.w),
                                  pk2(b.x,b.y), pk2(b.z,b.w));
}

// ---------------------------------------------------------------------------
// bf16 MFMA GEMM core: 128x128 tile, 3-buffer LDS pipeline with counted
// vmcnt (T3+T4): prefetch issued 2 K-steps ahead; raw s_barrier; the wait
// is vmcnt(8) -- only stage(t+1)'s 8 loads may remain outstanding -- never
// vmcnt(0) in the main loop. T2 XOR LDS swizzle (both-sides, rule #21).
// LDS: As/Bs each 3 x (128x64) bf16 = 96KB.
// epi: 0=none, 1=silu, 2=softplus
// ---------------------------------------------------------------------------
__device__ __forceinline__ void gemm_core(
    const short* __restrict__ Ab, const short* __restrict__ Bt,
    const float* __restrict__ bias, float* __restrict__ C,
    int Nn, int K, int bm0, int bn0, int epi,
    short* As, short* Bs)
{
  const int tid  = threadIdx.x;
  const int lane = tid & 63;
  const int w    = tid >> 6;          // wave 0..3
  const int wm0  = (w >> 1) * 64;
  const int wn0  = (w & 1) * 64;

  const int srow = tid >> 3;          // 0..31 (staging row)
  const int scol = ((tid & 7) ^ ((tid >> 3) & 7)) << 3;  // pre-swizzled src col

  const short* gA = Ab + (size_t)(bm0 + srow) * K + scol;
  const short* gB = Bt + (size_t)(bn0 + srow) * K + scol;
  char* ldsA = (char*)As;
  char* ldsB = (char*)Bs;
  const int wuni = w * 1024;          // wave-uniform LDS byte offset

  f32x4 acc[4][4];
  const f32x4 zz = {0.f, 0.f, 0.f, 0.f};
  #pragma unroll
  for (int m = 0; m < 4; m++)
    #pragma unroll
    for (int n = 0; n < 4; n++) acc[m][n] = zz;

  const int fr  = lane & 15;          // frag row (A) / col (B)
  const int ks  = (lane >> 4) << 3;   // frag k-offset (elems) within 32-slice
  const int swz = (fr & 7) << 3;      // T2 read-side XOR (elems)

  const int NT = K >> 6;

  // stage K-step t into buffer t%3 (8 global_load_lds per thread)
  auto STAGE = [&](int t) {
    const int ko = t << 6;
    const int bo = (t % 3) * 16384;   // bytes
    #pragma unroll
    for (int i = 0; i < 4; i++) {
      gload16(gA + (size_t)(i * 32) * K + ko, ldsA + bo + i * 4096 + wuni);
      gload16(gB + (size_t)(i * 32) * K + ko, ldsB + bo + i * 4096 + wuni);
    }
  };

  STAGE(0);
  STAGE(1);

  for (int t = 0; t < NT; ++t) {
    // wait for stage(t)'s loads (all but stage(t+1)'s 8 newest) -- then
    // barrier so EVERY wave's slice of buf[t%3] is known complete.
    if (t + 1 < NT) asm volatile("s_waitcnt vmcnt(8)" ::: "memory");
    else            asm volatile("s_waitcnt vmcnt(0)" ::: "memory");
    __builtin_amdgcn_s_barrier();
    if (t + 2 < NT) STAGE(t + 2);     // overwrites buf consumed at t-1: safe

    const short* Ac = As + (t % 3) * 8192;
    const short* Bc = Bs + (t % 3) * 8192;
    #pragma unroll
    for (int s = 0; s < 2; s++) {
      const int cs = ((s << 5) | ks) ^ swz;
      bf16x8 af[4], bf[4];
      #pragma unroll
      for (int m = 0; m < 4; m++)
        af[m] = *(const bf16x8*)&Ac[(wm0 + m*16 + fr) * 64 + cs];
      #pragma unroll
      for (int n = 0; n < 4; n++)
        bf[n] = *(const bf16x8*)&Bc[(wn0 + n*16 + fr) * 64 + cs];
      #pragma unroll
      for (int m = 0; m < 4; m++)
        #pragma unroll
        for (int n = 0; n < 4; n++)
          acc[m][n] = __builtin_amdgcn_mfma_f32_16x16x32_bf16(af[m], bf[n], acc[m][n], 0, 0, 0);
    }
  }

  // epilogue: C/D layout col = lane&15, row = (lane>>4)*4 + reg
  const int orow = (lane >> 4) * 4;
  const int ocol = lane & 15;
  #pragma unroll
  for (int n = 0; n < 4; n++) {
    const int col = bn0 + wn0 + n*16 + ocol;
    const float bv = bias[col];
    #pragma unroll
    for (int m = 0; m < 4; m++) {
      #pragma unroll
      for (int r = 0; r < 4; r++) {
        float v = acc[m][n][r] + bv;
        if (epi == 1) v = silu_f(v);
        else if (epi == 2) v = softplus_f(v);
        C[(size_t)(bm0 + wm0 + m*16 + orow + r) * Nn + col] = v;
      }
    }
  }
}

__global__ __launch_bounds__(256) void gemm_bf16_k(
    const short* __restrict__ Ab, const short* __restrict__ Bt,
    const float* __restrict__ bias, float* __restrict__ C,
    int Nn, int K, int epi)
{
  __shared__ short As[3*128*64];
  __shared__ short Bs[3*128*64];
  int2 p = xcd_swz(gridDim.x);
  gemm_core(Ab, Bt, bias, C, Nn, K, p.y * 128, p.x * 128, epi, As, Bs);
}

// fused in_proj + gate: grid (16,32); x<8 -> x1/no-act, x>=8 -> z/silu
__global__ __launch_bounds__(256) void gemm_ing_k(
    const short* __restrict__ ub,
    const short* __restrict__ Wti, const short* __restrict__ Wtg,
    const float* __restrict__ b_in, const float* __restrict__ bg,
    float* __restrict__ x1, float* __restrict__ z)
{
  __shared__ short As[3*128*64];
  __shared__ short Bs[3*128*64];
  int2 p = xcd_swz(gridDim.x);
  const int gate = p.x >> 3;
  gemm_core(ub, gate ? Wtg : Wti, gate ? bg : b_in, gate ? z : x1,
            DD, DD, p.y * 128, (p.x & 7) * 128, gate ? 1 : 0, As, Bs);
}

// ---------------------------------------------------------------------------
// Fused dt GEMM + B/C projections, 128x128 tiles, grid (8,32) = 256 blocks.
// Same 3-buffer counted-vmcnt pipeline; every block also computes the B/C
// tile for its rows [bm0 + bx*16, +16) x 32 from already-staged A-frags +
// a 4KB/step Wbct stage (9th load -> vmcnt(9)). Waves 0/1 hold the BC acc.
// ---------------------------------------------------------------------------
__global__ __launch_bounds__(256) void gemm_dtbc_k(
    const short* __restrict__ xb, const short* __restrict__ Wtd,
    const short* __restrict__ Wbct,
    const float* __restrict__ bdt, const float* __restrict__ bb,
    const float* __restrict__ bc,
    float* __restrict__ dt, float* __restrict__ Bm, float* __restrict__ Cm)
{
  __shared__ short As[3*128*64];
  __shared__ short Bs[3*128*64];
  __shared__ short Cs[3*32*64];
  int2 p = xcd_swz(gridDim.x);
  const int bx  = p.x;
  const int bm0 = p.y * 128;
  const int bn0 = bx * 128;

  const int tid  = threadIdx.x;
  const int lane = tid & 63;
  const int w    = tid >> 6;
  const int wm0  = (w >> 1) * 64;
  const int wn0  = (w & 1) * 64;

  const int srow = tid >> 3;
  const int scol = ((tid & 7) ^ ((tid >> 3) & 7)) << 3;

  const short* gA = xb   + (size_t)(bm0 + srow) * DD + scol;
  const short* gB = Wtd  + (size_t)(bn0 + srow) * DD + scol;
  const short* gC = Wbct + (size_t)srow * DD + scol;
  char* ldsA = (char*)As;
  char* ldsB = (char*)Bs;
  char* ldsC = (char*)Cs;
  const int wuni = w * 1024;

  f32x4 acc[4][4];
  const f32x4 zz = {0.f, 0.f, 0.f, 0.f};
  #pragma unroll
  for (int m = 0; m < 4; m++)
    #pragma unroll
    for (int n = 0; n < 4; n++) acc[m][n] = zz;
  f32x4 accbc = zz;

  const int fr  = lane & 15;
  const int ks  = (lane >> 4) << 3;
  const int swz = (fr & 7) << 3;

  auto STAGE = [&](int t) {
    const int ko = t << 6;
    const int bo = (t % 3) * 16384;
    #pragma unroll
    for (int i = 0; i < 4; i++) {
      gload16(gA + (size_t)(i * 32) * DD + ko, ldsA + bo + i * 4096 + wuni);
      gload16(gB + (size_t)(i * 32) * DD + ko, ldsB + bo + i * 4096 + wuni);
    }
    gload16(gC + ko, ldsC + (t % 3) * 4096 + wuni);   // 9th load
  };

  STAGE(0);
  STAGE(1);

  for (int t = 0; t < 16; ++t) {
    if (t + 1 < 16) asm volatile("s_waitcnt vmcnt(9)" ::: "memory");
    else            asm volatile("s_waitcnt vmcnt(0)" ::: "memory");
    __builtin_amdgcn_s_barrier();
    if (t + 2 < 16) STAGE(t + 2);

    const short* Ac = As + (t % 3) * 8192;
    const short* Bc = Bs + (t % 3) * 8192;
    const short* Cc = Cs + (t % 3) * 2048;
    #pragma unroll
    for (int s = 0; s < 2; s++) {
      const int cs = ((s << 5) | ks) ^ swz;
      bf16x8 af[4], bf[4];
      #pragma unroll
      for (int m = 0; m < 4; m++)
        af[m] = *(const bf16x8*)&Ac[(wm0 + m*16 + fr) * 64 + cs];
      #pragma unroll
      for (int n = 0; n < 4; n++)
        bf[n] = *(const bf16x8*)&Bc[(wn0 + n*16 + fr) * 64 + cs];
      #pragma unroll
      for (int m = 0; m < 4; m++)
        #pragma unroll
        for (int n = 0; n < 4; n++)
          acc[m][n] = __builtin_amdgcn_mfma_f32_16x16x32_bf16(af[m], bf[n], acc[m][n], 0, 0, 0);
      if (w < 2) {
        bf16x8 abc = *(const bf16x8*)&Ac[(bx*16 + fr) * 64 + cs];
        bf16x8 bbc = *(const bf16x8*)&Cc[((w << 4) + fr) * 64 + cs];
        accbc = __builtin_amdgcn_mfma_f32_16x16x32_bf16(abc, bbc, accbc, 0, 0, 0);
      }
    }
  }

  const int orow = (lane >> 4) * 4;
  const int ocol = lane & 15;
  #pragma unroll
  for (int n = 0; n < 4; n++) {
    const int col = bn0 + wn0 + n*16 + ocol;
    const float bv = bdt[col];
    #pragma unroll
    for (int m = 0; m < 4; m++) {
      #pragma unroll
      for (int r = 0; r < 4; r++) {
        float v = acc[m][n][r] + bv;
        dt[(size_t)(bm0 + wm0 + m*16 + orow + r) * DD + col] = softplus_f(v);
      }
    }
  }
  if (w < 2) {
    const float bv = (w == 0 ? bb : bc)[ocol];
    float* dst = (w == 0) ? Bm : Cm;
    #pragma unroll
    for (int r = 0; r < 4; r++) {
      int row = bm0 + bx*16 + orow + r;
      dst[(size_t)row * NNs + ocol] = accbc[r] + bv;
    }
  }
}

// ---------------------------------------------------------------------------
// Depthwise conv3 (same over T) + silu. Writes fp32 x and bf16 xb.
// ---------------------------------------------------------------------------
__global__ __launch_bounds__(256) void conv_silu(
    const float* __restrict__ x1, const float* __restrict__ cw,
    const float* __restrict__ cb, float* __restrict__ x,
    short* __restrict__ xb)
{
  int idx = blockIdx.x * 256 + threadIdx.x;       // over MM*DD/4
  int d4 = idx & (DD/4 - 1);
  int bt = idx >> 8;                              // DD/4 == 256
  int t  = bt & (TT - 1);
  const float4* b4 = (const float4*)x1;
  size_t ri = (size_t)bt * (DD/4) + d4;
  float4 zz = make_float4(0.f, 0.f, 0.f, 0.f);
  float4 vc = b4[ri];
  float4 vm = (t > 0)      ? b4[ri - DD/4] : zz;
  float4 vp = (t < TT - 1) ? b4[ri + DD/4] : zz;
  float rm[4] = {vm.x, vm.y, vm.z, vm.w};
  float rc[4] = {vc.x, vc.y, vc.z, vc.w};
  float rp[4] = {vp.x, vp.y, vp.z, vp.w};
  float o[4];
  #pragma unroll
  for (int j = 0; j < 4; j++) {
    int d = d4*4 + j;
    float v = rm[j]*cw[d*3+0] + rc[j]*cw[d*3+1] + rp[j]*cw[d*3+2] + cb[d];
    o[j] = silu_f(v);
  }
  ((float4*)x)[ri] = make_float4(o[0], o[1], o[2], o[3]);
  ((uint2*)xb)[ri] = make_uint2(pk2(o[0], o[1]), pk2(o[2], o[3]));
}

// ---------------------------------------------------------------------------
// Selective scan, 3-phase chunked (16 chunks of 64)
// ---------------------------------------------------------------------------
__global__ __launch_bounds__(256) void scan_local(
    const float* __restrict__ dt, const float* __restrict__ x,
    const float* __restrict__ Bm, const float* __restrict__ A,
    float* __restrict__ P, float* __restrict__ S)
{
  __shared__ float Bs[CHUNK*NNs];
  int bid = blockIdx.x;
  int dblk = bid & 3;
  int c = (bid >> 2) & 15;
  int b = bid >> 6;
  int d = dblk*256 + threadIdx.x;
  int t0 = c * CHUNK;
  for (int i = threadIdx.x; i < CHUNK*NNs; i += 256)
    Bs[i] = Bm[(size_t)(b*TT + t0)*NNs + i];
  float a[NNs];
  #pragma unroll
  for (int n = 0; n < NNs; n++) a[n] = A[d*NNs + n];
  __syncthreads();
  float h[NNs], p[NNs];
  #pragma unroll
  for (int n = 0; n < NNs; n++) { h[n] = 0.f; p[n] = 1.f; }
  size_t base = (size_t)(b*TT + t0)*DD + d;
  for (int tt = 0; tt < CHUNK; tt++) {
    float dtv = dt[base + (size_t)tt*DD];
    float xv  = x [base + (size_t)tt*DD];
    float dx = dtv * xv;
    #pragma unroll
    for (int n = 0; n < NNs; n++) {
      float e = __expf(dtv * a[n]);
      h[n] = fmaf(e, h[n], dx * Bs[tt*NNs + n]);
      p[n] *= e;
    }
  }
  size_t o = ((size_t)((b*NCHUNK + c)*DD + d)) * NNs;
  #pragma unroll
  for (int n = 0; n < NNs; n += 4) {
    *(float4*)&P[o+n] = make_float4(p[n], p[n+1], p[n+2], p[n+3]);
    *(float4*)&S[o+n] = make_float4(h[n], h[n+1], h[n+2], h[n+3]);
  }
}

__global__ __launch_bounds__(256) void scan_combine(
    const float* __restrict__ P, const float* __restrict__ S,
    float* __restrict__ H0)
{
  int g = blockIdx.x*256 + threadIdx.x;   // B*DD*NNs = 65536
  int n = g & 15; int d = (g >> 4) & 1023; int b = g >> 14;
  float h = 0.f;
  for (int c = 0; c < NCHUNK; c++) {
    size_t idx = ((size_t)((b*NCHUNK + c)*DD + d)) * NNs + n;
    H0[idx] = h;
    h = fmaf(P[idx], h, S[idx]);
  }
}

// Phase 3: replay with correct h0; y = <h,C>; fuse gate; write bf16 xsb
__global__ __launch_bounds__(256) void scan_y(
    const float* __restrict__ dt, const float* __restrict__ x,
    const float* __restrict__ Bm, const float* __restrict__ Cm,
    const float* __restrict__ A,  const float* __restrict__ H0,
    const float* __restrict__ z,  short* __restrict__ xsb)
{
  __shared__ float Bs[CHUNK*NNs];
  __shared__ float Cs[CHUNK*NNs];
  int bid = blockIdx.x;
  int dblk = bid & 3;
  int c = (bid >> 2) & 15;
  int b = bid >> 6;
  int d = dblk*256 + threadIdx.x;
  int t0 = c * CHUNK;
  for (int i = threadIdx.x; i < CHUNK*NNs; i += 256) {
    Bs[i] = Bm[(size_t)(b*TT + t0)*NNs + i];
    Cs[i] = Cm[(size_t)(b*TT + t0)*NNs + i];
  }
  float a[NNs];
  #pragma unroll
  for (int n = 0; n < NNs; n++) a[n] = A[d*NNs + n];
  size_t ho = ((size_t)((b*NCHUNK + c)*DD + d)) * NNs;
  float h[NNs];
  #pragma unroll
  for (int n = 0; n < NNs; n += 4) {
    float4 h4 = *(const float4*)&H0[ho+n];
    h[n] = h4.x; h[n+1] = h4.y; h[n+2] = h4.z; h[n+3] = h4.w;
  }
  __syncthreads();
  size_t base = (size_t)(b*TT + t0)*DD + d;
  for (int tt = 0; tt < CHUNK; tt++) {
    float dtv = dt[base + (size_t)tt*DD];
    float xv  = x [base + (size_t)tt*DD];
    float dx = dtv * xv;
    float y = 0.f;
    #pragma unroll
    for (int n = 0; n < NNs; n++) {
      float e = __expf(dtv * a[n]);
      h[n] = fmaf(e, h[n], dx * Bs[tt*NNs + n]);
      y = fmaf(h[n], Cs[tt*NNs + n], y);
    }
    size_t gi = base + (size_t)tt*DD;
    xsb[gi] = (short)f2bf(y * z[gi]);
  }
}

// ---------------------------------------------------------------------------
extern "C" void kernel_launch(void* const* d_in, const int* in_sizes, int n_in,
                              void* d_out, int out_size, void* d_ws, size_t ws_size,
                              hipStream_t stream)
{
  const float* u     = (const float*)d_in[0];
  const float* Win   = (const float*)d_in[1];
  const float* b_in  = (const float*)d_in[2];
  const float* Wg    = (const float*)d_in[3];
  const float* bg    = (const float*)d_in[4];
  const float* Wout  = (const float*)d_in[5];
  const float* bout  = (const float*)d_in[6];
  const float* convw = (const float*)d_in[7];
  const float* convb = (const float*)d_in[8];
  const float* A     = (const float*)d_in[9];
  const float* Wb    = (const float*)d_in[10];
  const float* bb    = (const float*)d_in[11];
  const float* Wc    = (const float*)d_in[12];
  const float* bc    = (const float*)d_in[13];
  const float* Wdt   = (const float*)d_in[14];
  const float* bdt   = (const float*)d_in[15];
  float* out = (float*)d_out;

  // workspace layout (~88.6 MB)
  float* ws = (float*)d_ws;
  float* x1 = ws;                         // [M,D] f32 (later reused for P/S/H0)
  float* z  = x1 + MMDD;                  // [M,D] f32
  float* x  = z  + MMDD;                  // [M,D] f32
  float* dt = x  + MMDD;                  // [M,D] f32
  float* Bm = dt + MMDD;                  // [M,N]
  float* Cm = Bm + (size_t)MM*NNs;        // [M,N]
  short* ub  = (short*)(Cm + (size_t)MM*NNs);  // [M,D] bf16
  short* xb  = ub  + MMDD;                // [M,D] bf16
  short* Wti = xb  + MMDD;                // [D,D] bf16 transposed
  short* Wtg = Wti + (size_t)DD*DD;
  short* Wtd = Wtg + (size_t)DD*DD;
  short* Wto = Wtd + (size_t)DD*DD;
  short* Wbct = Wto + (size_t)DD*DD;      // [32,D] bf16 (Wb^T | Wc^T)
  float* P  = x1;                         // reuse x1 region after conv
  float* S  = P + (size_t)BB*NCHUNK*DD*NNs;
  float* H0 = S + (size_t)BB*NCHUNK*DD*NNs;
  short* xsb = ub;                        // reuse ub region after in/gate GEMM

  // 0) weight prep (one z-batched dispatch + tiny B/C transpose) and u->bf16
  wconv_t4<<<dim3(DD/32, DD/32, 4), 256, 0, stream>>>(
      Win, Wg, Wdt, Wout, Wti, Wtg, Wtd, Wto);
  wbc_t<<<(32*DD)/256, 256, 0, stream>>>(Wb, Wc, Wbct);
  to_bf16<<<(MMDD/8)/256, 256, 0, stream>>>(u, ub);

  // 1) fused in_proj (x1) + gate (z, silu)  [grid (16,32) = 512 blocks]
  gemm_ing_k<<<dim3(16, MM/128), 256, 0, stream>>>(ub, Wti, Wtg, b_in, bg, x1, z);
  // 2) depthwise conv + silu -> x (f32) + xb (bf16)
  conv_silu<<<(MMDD/4)/256, 256, 0, stream>>>(x1, convw, convb, x, xb);
  // 3) dt = softplus(x@Wdt + bdt) AND Bm/Cm, grid (8,32) = 256 blocks
  gemm_dtbc_k<<<dim3(8, MM/128), 256, 0, stream>>>(
      xb, Wtd, Wbct, bdt, bb, bc, dt, Bm, Cm);
  // 4-6) chunked selective scan (+ gate fused in phase 3, writes bf16)
  scan_local  <<<BB*NCHUNK*(DD/256), 256, 0, stream>>>(dt, x, Bm, A, P, S);
  scan_combine<<<(BB*DD*NNs)/256,    256, 0, stream>>>(P, S, H0);
  scan_y      <<<BB*NCHUNK*(DD/256), 256, 0, stream>>>(dt, x, Bm, Cm, A, H0, z, xsb);
  // 7) out = xs @ Wout + bout  [grid (8,32) = 256 blocks]
  gemm_bf16_k<<<dim3(8, MM/128), 256, 0, stream>>>(xsb, Wto, bout, out, DD, DD, 0);
}

// Round 11
// 297.364 us; speedup vs baseline: 1.0672x; 1.0672x over previous
//
#include <hip/hip_runtime.h>
#include <hip/hip_bf16.h>
#include <math.h>

// Problem constants (B,T,D,N from the reference)
#define BB 4
#define TT 1024
#define DD 1024
#define NNs 16
#define MM (BB*TT)          // 4096 rows
#define MMDD ((size_t)MM*DD)
#define CHUNK 64
#define NCHUNK (TT/CHUNK)   // 16

typedef short bf16x8 __attribute__((ext_vector_type(8)));
typedef float f32x4  __attribute__((ext_vector_type(4)));

__device__ __forceinline__ float silu_f(float v)     { return v / (1.f + __expf(-v)); }
__device__ __forceinline__ float softplus_f(float v) { return fmaxf(v, 0.f) + log1pf(__expf(-fabsf(v))); }

// fp32 -> bf16 (RNE) as raw bits
__device__ __forceinline__ unsigned short f2bf(float f) {
  unsigned u = __builtin_bit_cast(unsigned, f);
  u += 0x7fffu + ((u >> 16) & 1u);
  return (unsigned short)(u >> 16);
}
__device__ __forceinline__ unsigned pk2(float a, float b) {
  return (unsigned)f2bf(a) | ((unsigned)f2bf(b) << 16);
}
__device__ __forceinline__ float bf2f(short s) {
  return __builtin_bit_cast(float, ((unsigned)(unsigned short)s) << 16);
}

// async global->LDS, 16B per lane; lds ptr must be wave-uniform
__device__ __forceinline__ void gload16(const void* g, void* l) {
  __builtin_amdgcn_global_load_lds(
      (const __attribute__((address_space(1))) unsigned*)g,
      (__attribute__((address_space(3))) unsigned*)l, 16, 0, 0);
}

// T1: bijective chunked XCD swizzle (m204).
__device__ __forceinline__ int2 xcd_swz(int gx) {
  int nwg  = gx * (int)gridDim.y;
  int orig = (int)blockIdx.y * gx + (int)blockIdx.x;
  int q = nwg >> 3, r = nwg & 7;
  int xcd = orig & 7, i = orig >> 3;
  int wg = (xcd < r ? xcd * (q + 1) : r * (q + 1) + (xcd - r) * q) + i;
  return make_int2(wg % gx, wg / gx);
}

// ---------------------------------------------------------------------------
// Weight convert+transpose x4: W[K][N] f32 -> Wt[N][K] bf16 (K=N=DD), z-batched
// ---------------------------------------------------------------------------
__global__ __launch_bounds__(256) void wconv_t4(
    const float* __restrict__ W0, const float* __restrict__ W1,
    const float* __restrict__ W2, const float* __restrict__ W3,
    short* __restrict__ o0, short* __restrict__ o1,
    short* __restrict__ o2, short* __restrict__ o3)
{
  const float* W; short* Wt;
  switch (blockIdx.z) {
    case 0:  W = W0; Wt = o0; break;
    case 1:  W = W1; Wt = o1; break;
    case 2:  W = W2; Wt = o2; break;
    default: W = W3; Wt = o3; break;
  }
  __shared__ float t[32][33];
  int n0 = blockIdx.x * 32, k0 = blockIdx.y * 32;
  int r  = threadIdx.x >> 3;
  int c4 = (threadIdx.x & 7) * 4;
  float4 v = *(const float4*)(W + (size_t)(k0 + r) * DD + n0 + c4);
  t[r][c4+0] = v.x; t[r][c4+1] = v.y; t[r][c4+2] = v.z; t[r][c4+3] = v.w;
  __syncthreads();
  short q0 = (short)f2bf(t[c4+0][r]);
  short q1 = (short)f2bf(t[c4+1][r]);
  short q2 = (short)f2bf(t[c4+2][r]);
  short q3 = (short)f2bf(t[c4+3][r]);
  *(short4*)(Wt + (size_t)(n0 + r) * DD + k0 + c4) = make_short4(q0, q1, q2, q3);
}

// Wb[D][16], Wc[D][16] f32 -> Wbct[32][D] bf16 (rows 0-15 = Wb^T, 16-31 = Wc^T)
__global__ __launch_bounds__(256) void wbc_t(
    const float* __restrict__ Wb, const float* __restrict__ Wc,
    short* __restrict__ Wbct)
{
  int idx = blockIdx.x * 256 + threadIdx.x;  // 32*1024 = 32768
  int k = idx & (DD - 1);
  int n = idx >> 10;
  const float* W = (n < 16) ? Wb : Wc;
  Wbct[(size_t)n * DD + k] = (short)f2bf(W[(size_t)k * NNs + (n & 15)]);
}

// fp32 -> bf16 bulk convert (8 elems/thread)
__global__ __launch_bounds__(256) void to_bf16(
    const float* __restrict__ in, short* __restrict__ out)
{
  size_t i = (size_t)(blockIdx.x * 256 + threadIdx.x) * 8;
  float4 a = *(const float4*)(in + i);
  float4 b = *(const float4*)(in + i + 4);
  *(uint4*)(out + i) = make_uint4(pk2(a.x,a.y), pk2(a.z,a.w),
                                  pk2(b.x,b.y), pk2(b.z,b.w));
}

// ---------------------------------------------------------------------------
// bf16 MFMA GEMM core, R8 structure: 128x128 tile, 2-phase double-buffered
// (64KB LDS -> 2 resident blocks/CU), T2 XOR LDS swizzle (both-sides).
// kBase/kLen select a K-range (for split-K). bias==nullptr -> raw output.
// epi: 0=none, 1=silu, 2=softplus
// ---------------------------------------------------------------------------
__device__ __forceinline__ void gemm_core(
    const short* __restrict__ Ab, const short* __restrict__ Bt,
    const float* __restrict__ bias, float* __restrict__ C,
    int Nn, int K, int kBase, int kLen, int bm0, int bn0, int epi,
    short* As, short* Bs)
{
  const int tid  = threadIdx.x;
  const int lane = tid & 63;
  const int w    = tid >> 6;          // wave 0..3
  const int wm0  = (w >> 1) * 64;
  const int wn0  = (w & 1) * 64;

  const int srow = tid >> 3;          // 0..31 (staging row)
  const int scol = ((tid & 7) ^ ((tid >> 3) & 7)) << 3;  // pre-swizzled src col

  const short* gA = Ab + (size_t)(bm0 + srow) * K + kBase + scol;
  const short* gB = Bt + (size_t)(bn0 + srow) * K + kBase + scol;
  char* ldsA = (char*)As;
  char* ldsB = (char*)Bs;
  const int wuni = w * 1024;          // wave-uniform LDS byte offset

  f32x4 acc[4][4];
  const f32x4 zz = {0.f, 0.f, 0.f, 0.f};
  #pragma unroll
  for (int m = 0; m < 4; m++)
    #pragma unroll
    for (int n = 0; n < 4; n++) acc[m][n] = zz;

  const int fr  = lane & 15;          // frag row (A) / col (B)
  const int ks  = (lane >> 4) << 3;   // frag k-offset (elems) within 32-slice
  const int swz = (fr & 7) << 3;      // T2 read-side XOR (elems)

  const int NT = kLen >> 6;

  // prologue: stage tile 0 into buf 0
  #pragma unroll
  for (int i = 0; i < 4; i++) {
    gload16(gA + (size_t)(i * 32) * K, ldsA + i * 4096 + wuni);
    gload16(gB + (size_t)(i * 32) * K, ldsB + i * 4096 + wuni);
  }
  __syncthreads();

  for (int t = 0; t < NT; ++t) {
    const int cur = t & 1;
    if (t + 1 < NT) {                 // prefetch next tile into other buf
      const int k1 = (t + 1) << 6;
      const int bo = (cur ^ 1) * 16384;
      #pragma unroll
      for (int i = 0; i < 4; i++) {
        gload16(gA + (size_t)(i * 32) * K + k1, ldsA + bo + i * 4096 + wuni);
        gload16(gB + (size_t)(i * 32) * K + k1, ldsB + bo + i * 4096 + wuni);
      }
    }
    const short* Ac = As + cur * 8192;
    const short* Bc = Bs + cur * 8192;
    #pragma unroll
    for (int s = 0; s < 2; s++) {
      const int cs = ((s << 5) | ks) ^ swz;
      bf16x8 af[4], bf[4];
      #pragma unroll
      for (int m = 0; m < 4; m++)
        af[m] = *(const bf16x8*)&Ac[(wm0 + m*16 + fr) * 64 + cs];
      #pragma unroll
      for (int n = 0; n < 4; n++)
        bf[n] = *(const bf16x8*)&Bc[(wn0 + n*16 + fr) * 64 + cs];
      #pragma unroll
      for (int m = 0; m < 4; m++)
        #pragma unroll
        for (int n = 0; n < 4; n++)
          acc[m][n] = __builtin_amdgcn_mfma_f32_16x16x32_bf16(af[m], bf[n], acc[m][n], 0, 0, 0);
    }
    __syncthreads();
  }

  // epilogue: C/D layout col = lane&15, row = (lane>>4)*4 + reg
  const int orow = (lane >> 4) * 4;
  const int ocol = lane & 15;
  #pragma unroll
  for (int n = 0; n < 4; n++) {
    const int col = bn0 + wn0 + n*16 + ocol;
    const float bv = bias ? bias[col] : 0.f;
    #pragma unroll
    for (int m = 0; m < 4; m++) {
      #pragma unroll
      for (int r = 0; r < 4; r++) {
        float v = acc[m][n][r] + bv;
        if (epi == 1) v = silu_f(v);
        else if (epi == 2) v = softplus_f(v);
        C[(size_t)(bm0 + wm0 + m*16 + orow + r) * Nn + col] = v;
      }
    }
  }
}

// fused in_proj + gate: grid (16,32); x<8 -> x1/no-act, x>=8 -> z/silu
__global__ __launch_bounds__(256) void gemm_ing_k(
    const short* __restrict__ ub,
    const short* __restrict__ Wti, const short* __restrict__ Wtg,
    const float* __restrict__ b_in, const float* __restrict__ bg,
    float* __restrict__ x1, float* __restrict__ z)
{
  __shared__ short As[2*128*64];
  __shared__ short Bs[2*128*64];
  int2 p = xcd_swz(gridDim.x);
  const int gate = p.x >> 3;
  gemm_core(ub, gate ? Wtg : Wti, gate ? bg : b_in, gate ? z : x1,
            DD, DD, 0, DD, p.y * 128, (p.x & 7) * 128, gate ? 1 : 0, As, Bs);
}

// out GEMM, split-K=2: grid (8,32,2). z picks K-half and partial buffer. Raw.
__global__ __launch_bounds__(256) void gemm_out_k(
    const short* __restrict__ xsb, const short* __restrict__ Wto,
    float* __restrict__ O0, float* __restrict__ O1)
{
  __shared__ short As[2*128*64];
  __shared__ short Bs[2*128*64];
  int2 p = xcd_swz(gridDim.x);
  const int s = blockIdx.z;
  gemm_core(xsb, Wto, nullptr, s ? O1 : O0,
            DD, DD, s * 512, 512, p.y * 128, p.x * 128, 0, As, Bs);
}

// ---------------------------------------------------------------------------
// Fused dt GEMM + B/C projections, split-K=2: grid (8,32,2) = 512 blocks
// (2 resident/CU). Raw partials: d{0,1}[M,D]; B{0,1}/C{0,1}[M,16].
// Bias + softplus fold into the scan kernels. BC tile: block covers rows
// [bm0+bx*16,+16) x 32 from already-staged A-frags + 4KB Wbct stage.
// ---------------------------------------------------------------------------
__global__ __launch_bounds__(256) void gemm_dtbc_k(
    const short* __restrict__ xb, const short* __restrict__ Wtd,
    const short* __restrict__ Wbct,
    float* __restrict__ d0, float* __restrict__ d1,
    float* __restrict__ B0, float* __restrict__ B1,
    float* __restrict__ C0, float* __restrict__ C1)
{
  __shared__ short As[2*128*64];
  __shared__ short Bs[2*128*64];
  __shared__ short Cs[2*32*64];
  int2 p = xcd_swz(gridDim.x);
  const int sp  = blockIdx.z;         // K-split half
  const int kB  = sp * 512;
  const int bx  = p.x;
  const int bm0 = p.y * 128;
  const int bn0 = bx * 128;
  float* dOut = sp ? d1 : d0;
  float* bOut = sp ? B1 : B0;
  float* cOut = sp ? C1 : C0;

  const int tid  = threadIdx.x;
  const int lane = tid & 63;
  const int w    = tid >> 6;
  const int wm0  = (w >> 1) * 64;
  const int wn0  = (w & 1) * 64;

  const int srow = tid >> 3;
  const int scol = ((tid & 7) ^ ((tid >> 3) & 7)) << 3;

  const short* gA = xb   + (size_t)(bm0 + srow) * DD + kB + scol;
  const short* gB = Wtd  + (size_t)(bn0 + srow) * DD + kB + scol;
  const short* gC = Wbct + (size_t)srow * DD + kB + scol;
  char* ldsA = (char*)As;
  char* ldsB = (char*)Bs;
  char* ldsC = (char*)Cs;
  const int wuni = w * 1024;

  f32x4 acc[4][4];
  const f32x4 zz = {0.f, 0.f, 0.f, 0.f};
  #pragma unroll
  for (int m = 0; m < 4; m++)
    #pragma unroll
    for (int n = 0; n < 4; n++) acc[m][n] = zz;
  f32x4 accbc = zz;

  const int fr  = lane & 15;
  const int ks  = (lane >> 4) << 3;
  const int swz = (fr & 7) << 3;

  // prologue
  #pragma unroll
  for (int i = 0; i < 4; i++) {
    gload16(gA + (size_t)(i * 32) * DD, ldsA + i * 4096 + wuni);
    gload16(gB + (size_t)(i * 32) * DD, ldsB + i * 4096 + wuni);
  }
  gload16(gC, ldsC + wuni);
  __syncthreads();

  for (int t = 0; t < 8; ++t) {
    const int cur = t & 1;
    if (t + 1 < 8) {
      const int k1 = (t + 1) << 6;
      const int bo = (cur ^ 1) * 16384;
      #pragma unroll
      for (int i = 0; i < 4; i++) {
        gload16(gA + (size_t)(i * 32) * DD + k1, ldsA + bo + i * 4096 + wuni);
        gload16(gB + (size_t)(i * 32) * DD + k1, ldsB + bo + i * 4096 + wuni);
      }
      gload16(gC + k1, ldsC + (cur ^ 1) * 4096 + wuni);
    }
    const short* Ac = As + cur * 8192;
    const short* Bc = Bs + cur * 8192;
    const short* Cc = Cs + cur * 2048;
    #pragma unroll
    for (int s = 0; s < 2; s++) {
      const int cs = ((s << 5) | ks) ^ swz;
      bf16x8 af[4], bf[4];
      #pragma unroll
      for (int m = 0; m < 4; m++)
        af[m] = *(const bf16x8*)&Ac[(wm0 + m*16 + fr) * 64 + cs];
      #pragma unroll
      for (int n = 0; n < 4; n++)
        bf[n] = *(const bf16x8*)&Bc[(wn0 + n*16 + fr) * 64 + cs];
      #pragma unroll
      for (int m = 0; m < 4; m++)
        #pragma unroll
        for (int n = 0; n < 4; n++)
          acc[m][n] = __builtin_amdgcn_mfma_f32_16x16x32_bf16(af[m], bf[n], acc[m][n], 0, 0, 0);
      if (w < 2) {
        bf16x8 abc = *(const bf16x8*)&Ac[(bx*16 + fr) * 64 + cs];
        bf16x8 bbc = *(const bf16x8*)&Cc[((w << 4) + fr) * 64 + cs];
        accbc = __builtin_amdgcn_mfma_f32_16x16x32_bf16(abc, bbc, accbc, 0, 0, 0);
      }
    }
    __syncthreads();
  }

  const int orow = (lane >> 4) * 4;
  const int ocol = lane & 15;
  #pragma unroll
  for (int n = 0; n < 4; n++) {
    const int col = bn0 + wn0 + n*16 + ocol;
    #pragma unroll
    for (int m = 0; m < 4; m++) {
      #pragma unroll
      for (int r = 0; r < 4; r++)
        dOut[(size_t)(bm0 + wm0 + m*16 + orow + r) * DD + col] = acc[m][n][r];
    }
  }
  if (w < 2) {
    float* dst = (w == 0) ? bOut : cOut;
    #pragma unroll
    for (int r = 0; r < 4; r++) {
      int row = bm0 + bx*16 + orow + r;
      dst[(size_t)row * NNs + ocol] = accbc[r];
    }
  }
}

// ---------------------------------------------------------------------------
// Depthwise conv3 (same over T) + silu -> bf16 xb only.
// ---------------------------------------------------------------------------
__global__ __launch_bounds__(256) void conv_silu(
    const float* __restrict__ x1, const float* __restrict__ cw,
    const float* __restrict__ cb, short* __restrict__ xb)
{
  int idx = blockIdx.x * 256 + threadIdx.x;       // over MM*DD/4
  int d4 = idx & (DD/4 - 1);
  int bt = idx >> 8;                              // DD/4 == 256
  int t  = bt & (TT - 1);
  const float4* b4 = (const float4*)x1;
  size_t ri = (size_t)bt * (DD/4) + d4;
  float4 zz = make_float4(0.f, 0.f, 0.f, 0.f);
  float4 vc = b4[ri];
  float4 vm = (t > 0)      ? b4[ri - DD/4] : zz;
  float4 vp = (t < TT - 1) ? b4[ri + DD/4] : zz;
  float rm[4] = {vm.x, vm.y, vm.z, vm.w};
  float rc[4] = {vc.x, vc.y, vc.z, vc.w};
  float rp[4] = {vp.x, vp.y, vp.z, vp.w};
  float o[4];
  #pragma unroll
  for (int j = 0; j < 4; j++) {
    int d = d4*4 + j;
    float v = rm[j]*cw[d*3+0] + rc[j]*cw[d*3+1] + rp[j]*cw[d*3+2] + cb[d];
    o[j] = silu_f(v);
  }
  ((uint2*)xb)[ri] = make_uint2(pk2(o[0], o[1]), pk2(o[2], o[3]));
}

// ---------------------------------------------------------------------------
// Selective scan, 3-phase chunked (16 chunks of 64). dt/B/C fold the split
// partials + bias (+softplus for dt) at load; x comes from bf16 xb.
// ---------------------------------------------------------------------------
__global__ __launch_bounds__(256) void scan_local(
    const float* __restrict__ d0, const float* __restrict__ d1,
    const float* __restrict__ bdt, const short* __restrict__ xb,
    const float* __restrict__ B0, const float* __restrict__ B1,
    const float* __restrict__ bb, const float* __restrict__ A,
    float* __restrict__ P, float* __restrict__ S)
{
  __shared__ float Bsh[CHUNK*NNs];
  int bid = blockIdx.x;
  int dblk = bid & 3;
  int c = (bid >> 2) & 15;
  int b = bid >> 6;
  int d = dblk*256 + threadIdx.x;
  int t0 = c * CHUNK;
  size_t bo = (size_t)(b*TT + t0)*NNs;
  for (int i = threadIdx.x; i < CHUNK*NNs; i += 256)
    Bsh[i] = B0[bo + i] + B1[bo + i] + bb[i & 15];
  float a[NNs];
  #pragma unroll
  for (int n = 0; n < NNs; n++) a[n] = A[d*NNs + n];
  const float bdtv = bdt[d];
  __syncthreads();
  float h[NNs], p[NNs];
  #pragma unroll
  for (int n = 0; n < NNs; n++) { h[n] = 0.f; p[n] = 1.f; }
  size_t base = (size_t)(b*TT + t0)*DD + d;
  for (int tt = 0; tt < CHUNK; tt++) {
    size_t gi = base + (size_t)tt*DD;
    float dtv = softplus_f(d0[gi] + d1[gi] + bdtv);
    float xv  = bf2f(xb[gi]);
    float dx = dtv * xv;
    #pragma unroll
    for (int n = 0; n < NNs; n++) {
      float e = __expf(dtv * a[n]);
      h[n] = fmaf(e, h[n], dx * Bsh[tt*NNs + n]);
      p[n] *= e;
    }
  }
  size_t o = ((size_t)((b*NCHUNK + c)*DD + d)) * NNs;
  #pragma unroll
  for (int n = 0; n < NNs; n += 4) {
    *(float4*)&P[o+n] = make_float4(p[n], p[n+1], p[n+2], p[n+3]);
    *(float4*)&S[o+n] = make_float4(h[n], h[n+1], h[n+2], h[n+3]);
  }
}

__global__ __launch_bounds__(256) void scan_combine(
    const float* __restrict__ P, const float* __restrict__ S,
    float* __restrict__ H0)   // may alias P (read-before-write per idx)
{
  int g = blockIdx.x*256 + threadIdx.x;   // B*DD*NNs = 65536
  int n = g & 15; int d = (g >> 4) & 1023; int b = g >> 14;
  float h = 0.f;
  for (int c = 0; c < NCHUNK; c++) {
    size_t idx = ((size_t)((b*NCHUNK + c)*DD + d)) * NNs + n;
    float pv = P[idx], sv = S[idx];
    H0[idx] = h;
    h = fmaf(pv, h, sv);
  }
}

// Phase 3: replay with correct h0; y = <h,C>; fuse gate; write bf16 xsb
__global__ __launch_bounds__(256) void scan_y(
    const float* __restrict__ d0, const float* __restrict__ d1,
    const float* __restrict__ bdt, const short* __restrict__ xb,
    const float* __restrict__ B0, const float* __restrict__ B1,
    const float* __restrict__ bb,
    const float* __restrict__ C0, const float* __restrict__ C1,
    const float* __restrict__ bc,
    const float* __restrict__ A,  const float* __restrict__ H0,
    const float* __restrict__ z,  short* __restrict__ xsb)
{
  __shared__ float Bsh[CHUNK*NNs];
  __shared__ float Csh[CHUNK*NNs];
  int bid = blockIdx.x;
  int dblk = bid & 3;
  int c = (bid >> 2) & 15;
  int b = bid >> 6;
  int d = dblk*256 + threadIdx.x;
  int t0 = c * CHUNK;
  size_t bo = (size_t)(b*TT + t0)*NNs;
  for (int i = threadIdx.x; i < CHUNK*NNs; i += 256) {
    Bsh[i] = B0[bo + i] + B1[bo + i] + bb[i & 15];
    Csh[i] = C0[bo + i] + C1[bo + i] + bc[i & 15];
  }
  float a[NNs];
  #pragma unroll
  for (int n = 0; n < NNs; n++) a[n] = A[d*NNs + n];
  const float bdtv = bdt[d];
  size_t ho = ((size_t)((b*NCHUNK + c)*DD + d)) * NNs;
  float h[NNs];
  #pragma unroll
  for (int n = 0; n < NNs; n += 4) {
    float4 h4 = *(const float4*)&H0[ho+n];
    h[n] = h4.x; h[n+1] = h4.y; h[n+2] = h4.z; h[n+3] = h4.w;
  }
  __syncthreads();
  size_t base = (size_t)(b*TT + t0)*DD + d;
  for (int tt = 0; tt < CHUNK; tt++) {
    size_t gi = base + (size_t)tt*DD;
    float dtv = softplus_f(d0[gi] + d1[gi] + bdtv);
    float xv  = bf2f(xb[gi]);
    float dx = dtv * xv;
    float y = 0.f;
    #pragma unroll
    for (int n = 0; n < NNs; n++) {
      float e = __expf(dtv * a[n]);
      h[n] = fmaf(e, h[n], dx * Bsh[tt*NNs + n]);
      y = fmaf(h[n], Csh[tt*NNs + n], y);
    }
    xsb[gi] = (short)f2bf(y * z[gi]);
  }
}

// out = O0 + O1 + bout  (float4, 4 elems/thread)
__global__ __launch_bounds__(256) void out_epi(
    const float* __restrict__ O0, const float* __restrict__ O1,
    const float* __restrict__ bout, float* __restrict__ out)
{
  size_t i = (size_t)(blockIdx.x * 256 + threadIdx.x) * 4;
  int col = (int)(i & (DD - 1));
  float4 a = *(const float4*)(O0 + i);
  float4 b = *(const float4*)(O1 + i);
  float4 bv = *(const float4*)(bout + col);
  *(float4*)(out + i) = make_float4(a.x + b.x + bv.x, a.y + b.y + bv.y,
                                    a.z + b.z + bv.z, a.w + b.w + bv.w);
}

// ---------------------------------------------------------------------------
extern "C" void kernel_launch(void* const* d_in, const int* in_sizes, int n_in,
                              void* d_out, int out_size, void* d_ws, size_t ws_size,
                              hipStream_t stream)
{
  const float* u     = (const float*)d_in[0];
  const float* Win   = (const float*)d_in[1];
  const float* b_in  = (const float*)d_in[2];
  const float* Wg    = (const float*)d_in[3];
  const float* bg    = (const float*)d_in[4];
  const float* Wout  = (const float*)d_in[5];
  const float* bout  = (const float*)d_in[6];
  const float* convw = (const float*)d_in[7];
  const float* convb = (const float*)d_in[8];
  const float* A     = (const float*)d_in[9];
  const float* Wb    = (const float*)d_in[10];
  const float* bb    = (const float*)d_in[11];
  const float* Wc    = (const float*)d_in[12];
  const float* bc    = (const float*)d_in[13];
  const float* Wdt   = (const float*)d_in[14];
  const float* bdt   = (const float*)d_in[15];
  float* out = (float*)d_out;

  // workspace layout (~89 MB)
  float* ws = (float*)d_ws;
  float* x1 = ws;                         // [M,D] f32; P/S/H0 overlay later
  float* z  = x1 + MMDD;                  // [M,D] f32 (gate, silu'd)
  float* d0 = z  + MMDD;                  // [M,D] f32 dt partial 0; O0 overlays
  float* d1 = d0 + MMDD;                  // [M,D] f32 dt partial 1; O1 overlays
  float* B0 = d1 + MMDD;                  // [M,16] x4 partials
  float* B1 = B0 + (size_t)MM*NNs;
  float* C0 = B1 + (size_t)MM*NNs;
  float* C1 = C0 + (size_t)MM*NNs;
  short* ub  = (short*)(C1 + (size_t)MM*NNs);  // [M,D] bf16
  short* xb  = ub  + MMDD;                // [M,D] bf16
  short* Wti = xb  + MMDD;                // [D,D] bf16 transposed x4
  short* Wtg = Wti + (size_t)DD*DD;
  short* Wtd = Wtg + (size_t)DD*DD;
  short* Wto = Wtd + (size_t)DD*DD;
  short* Wbct = Wto + (size_t)DD*DD;      // [32,D] bf16 (Wb^T | Wc^T)
  float* P  = x1;                         // 4MB, overlays x1 (dead after conv)
  float* S  = P + (size_t)BB*NCHUNK*DD*NNs;
  float* H0 = P;                          // combine is alias-safe (read first)
  float* O0 = d0;                         // out partials overlay d0/d1
  float* O1 = d1;
  short* xsb = ub;                        // reuse ub after in/gate GEMM

  // 0) weight prep + u->bf16
  wconv_t4<<<dim3(DD/32, DD/32, 4), 256, 0, stream>>>(
      Win, Wg, Wdt, Wout, Wti, Wtg, Wtd, Wto);
  wbc_t<<<(32*DD)/256, 256, 0, stream>>>(Wb, Wc, Wbct);
  to_bf16<<<(MMDD/8)/256, 256, 0, stream>>>(u, ub);

  // 1) fused in_proj (x1) + gate (z, silu)  [512 blocks = 2/CU]
  gemm_ing_k<<<dim3(16, MM/128), 256, 0, stream>>>(ub, Wti, Wtg, b_in, bg, x1, z);
  // 2) depthwise conv + silu -> xb (bf16)
  conv_silu<<<(MMDD/4)/256, 256, 0, stream>>>(x1, convw, convb, xb);
  // 3) dt partials + B/C partials, split-K=2 [512 blocks = 2/CU]
  gemm_dtbc_k<<<dim3(8, MM/128, 2), 256, 0, stream>>>(
      xb, Wtd, Wbct, d0, d1, B0, B1, C0, C1);
  // 4-6) chunked selective scan (folds partial sums + biases + softplus)
  scan_local  <<<BB*NCHUNK*(DD/256), 256, 0, stream>>>(
      d0, d1, bdt, xb, B0, B1, bb, A, P, S);
  scan_combine<<<(BB*DD*NNs)/256, 256, 0, stream>>>(P, S, H0);
  scan_y      <<<BB*NCHUNK*(DD/256), 256, 0, stream>>>(
      d0, d1, bdt, xb, B0, B1, bb, C0, C1, bc, A, H0, z, xsb);
  // 7) out partials, split-K=2 [512 blocks = 2/CU]  (O0/O1 overlay d0/d1)
  gemm_out_k<<<dim3(8, MM/128, 2), 256, 0, stream>>>(xsb, Wto, O0, O1);
  // 8) out = O0 + O1 + bout
  out_epi<<<(MMDD/4)/256, 256, 0, stream>>>(O0, O1, bout, out);
}

// Round 12
// 249.317 us; speedup vs baseline: 1.2729x; 1.1927x over previous
//
#include <hip/hip_runtime.h>
#include <hip/hip_bf16.h>
#include <math.h>

// Problem constants (B,T,D,N from the reference)
#define BB 4
#define TT 1024
#define DD 1024
#define NNs 16
#define MM (BB*TT)          // 4096 rows
#define MMDD ((size_t)MM*DD)
#define CHUNK 32
#define NCHUNK (TT/CHUNK)   // 32

typedef short bf16x8 __attribute__((ext_vector_type(8)));
typedef float f32x4  __attribute__((ext_vector_type(4)));

__device__ __forceinline__ float silu_f(float v)     { return v / (1.f + __expf(-v)); }
__device__ __forceinline__ float softplus_f(float v) { return fmaxf(v, 0.f) + log1pf(__expf(-fabsf(v))); }

// fp32 -> bf16 (RNE) as raw bits
__device__ __forceinline__ unsigned short f2bf(float f) {
  unsigned u = __builtin_bit_cast(unsigned, f);
  u += 0x7fffu + ((u >> 16) & 1u);
  return (unsigned short)(u >> 16);
}
__device__ __forceinline__ unsigned pk2(float a, float b) {
  return (unsigned)f2bf(a) | ((unsigned)f2bf(b) << 16);
}
__device__ __forceinline__ float bf2f(short s) {
  return __builtin_bit_cast(float, ((unsigned)(unsigned short)s) << 16);
}

// async global->LDS, 16B per lane; lds ptr must be wave-uniform
__device__ __forceinline__ void gload16(const void* g, void* l) {
  __builtin_amdgcn_global_load_lds(
      (const __attribute__((address_space(1))) unsigned*)g,
      (__attribute__((address_space(3))) unsigned*)l, 16, 0, 0);
}

// T1: bijective chunked XCD swizzle (m204).
__device__ __forceinline__ int2 xcd_swz(int gx) {
  int nwg  = gx * (int)gridDim.y;
  int orig = (int)blockIdx.y * gx + (int)blockIdx.x;
  int q = nwg >> 3, r = nwg & 7;
  int xcd = orig & 7, i = orig >> 3;
  int wg = (xcd < r ? xcd * (q + 1) : r * (q + 1) + (xcd - r) * q) + i;
  return make_int2(wg % gx, wg / gx);
}

// ---------------------------------------------------------------------------
// Weight convert+transpose x4: W[K][N] f32 -> Wt[N][K] bf16 (K=N=DD), z-batched
// ---------------------------------------------------------------------------
__global__ __launch_bounds__(256) void wconv_t4(
    const float* __restrict__ W0, const float* __restrict__ W1,
    const float* __restrict__ W2, const float* __restrict__ W3,
    short* __restrict__ o0, short* __restrict__ o1,
    short* __restrict__ o2, short* __restrict__ o3)
{
  const float* W; short* Wt;
  switch (blockIdx.z) {
    case 0:  W = W0; Wt = o0; break;
    case 1:  W = W1; Wt = o1; break;
    case 2:  W = W2; Wt = o2; break;
    default: W = W3; Wt = o3; break;
  }
  __shared__ float t[32][33];
  int n0 = blockIdx.x * 32, k0 = blockIdx.y * 32;
  int r  = threadIdx.x >> 3;
  int c4 = (threadIdx.x & 7) * 4;
  float4 v = *(const float4*)(W + (size_t)(k0 + r) * DD + n0 + c4);
  t[r][c4+0] = v.x; t[r][c4+1] = v.y; t[r][c4+2] = v.z; t[r][c4+3] = v.w;
  __syncthreads();
  short q0 = (short)f2bf(t[c4+0][r]);
  short q1 = (short)f2bf(t[c4+1][r]);
  short q2 = (short)f2bf(t[c4+2][r]);
  short q3 = (short)f2bf(t[c4+3][r]);
  *(short4*)(Wt + (size_t)(n0 + r) * DD + k0 + c4) = make_short4(q0, q1, q2, q3);
}

// Wb[D][16], Wc[D][16] f32 -> Wbct[32][D] bf16 (rows 0-15 = Wb^T, 16-31 = Wc^T)
__global__ __launch_bounds__(256) void wbc_t(
    const float* __restrict__ Wb, const float* __restrict__ Wc,
    short* __restrict__ Wbct)
{
  int idx = blockIdx.x * 256 + threadIdx.x;  // 32*1024 = 32768
  int k = idx & (DD - 1);
  int n = idx >> 10;
  const float* W = (n < 16) ? Wb : Wc;
  Wbct[(size_t)n * DD + k] = (short)f2bf(W[(size_t)k * NNs + (n & 15)]);
}

// fp32 -> bf16 bulk convert (8 elems/thread)
__global__ __launch_bounds__(256) void to_bf16(
    const float* __restrict__ in, short* __restrict__ out)
{
  size_t i = (size_t)(blockIdx.x * 256 + threadIdx.x) * 8;
  float4 a = *(const float4*)(in + i);
  float4 b = *(const float4*)(in + i + 4);
  *(uint4*)(out + i) = make_uint4(pk2(a.x,a.y), pk2(a.z,a.w),
                                  pk2(b.x,b.y), pk2(b.z,b.w));
}

// ---------------------------------------------------------------------------
// bf16 MFMA GEMM core, R8 structure: 128x128 tile, 2-phase double-buffered
// (64KB LDS -> 2 resident blocks/CU), T2 XOR LDS swizzle (both-sides).
// kBase/kLen select a K-range (for split-K). bias==nullptr -> raw output.
// epi: 0=none, 1=silu, 2=softplus
// ---------------------------------------------------------------------------
__device__ __forceinline__ void gemm_core(
    const short* __restrict__ Ab, const short* __restrict__ Bt,
    const float* __restrict__ bias, float* __restrict__ C,
    int Nn, int K, int kBase, int kLen, int bm0, int bn0, int epi,
    short* As, short* Bs)
{
  const int tid  = threadIdx.x;
  const int lane = tid & 63;
  const int w    = tid >> 6;          // wave 0..3
  const int wm0  = (w >> 1) * 64;
  const int wn0  = (w & 1) * 64;

  const int srow = tid >> 3;          // 0..31 (staging row)
  const int scol = ((tid & 7) ^ ((tid >> 3) & 7)) << 3;  // pre-swizzled src col

  const short* gA = Ab + (size_t)(bm0 + srow) * K + kBase + scol;
  const short* gB = Bt + (size_t)(bn0 + srow) * K + kBase + scol;
  char* ldsA = (char*)As;
  char* ldsB = (char*)Bs;
  const int wuni = w * 1024;          // wave-uniform LDS byte offset

  f32x4 acc[4][4];
  const f32x4 zz = {0.f, 0.f, 0.f, 0.f};
  #pragma unroll
  for (int m = 0; m < 4; m++)
    #pragma unroll
    for (int n = 0; n < 4; n++) acc[m][n] = zz;

  const int fr  = lane & 15;          // frag row (A) / col (B)
  const int ks  = (lane >> 4) << 3;   // frag k-offset (elems) within 32-slice
  const int swz = (fr & 7) << 3;      // T2 read-side XOR (elems)

  const int NT = kLen >> 6;

  // prologue: stage tile 0 into buf 0
  #pragma unroll
  for (int i = 0; i < 4; i++) {
    gload16(gA + (size_t)(i * 32) * K, ldsA + i * 4096 + wuni);
    gload16(gB + (size_t)(i * 32) * K, ldsB + i * 4096 + wuni);
  }
  __syncthreads();

  for (int t = 0; t < NT; ++t) {
    const int cur = t & 1;
    if (t + 1 < NT) {                 // prefetch next tile into other buf
      const int k1 = (t + 1) << 6;
      const int bo = (cur ^ 1) * 16384;
      #pragma unroll
      for (int i = 0; i < 4; i++) {
        gload16(gA + (size_t)(i * 32) * K + k1, ldsA + bo + i * 4096 + wuni);
        gload16(gB + (size_t)(i * 32) * K + k1, ldsB + bo + i * 4096 + wuni);
      }
    }
    const short* Ac = As + cur * 8192;
    const short* Bc = Bs + cur * 8192;
    #pragma unroll
    for (int s = 0; s < 2; s++) {
      const int cs = ((s << 5) | ks) ^ swz;
      bf16x8 af[4], bf[4];
      #pragma unroll
      for (int m = 0; m < 4; m++)
        af[m] = *(const bf16x8*)&Ac[(wm0 + m*16 + fr) * 64 + cs];
      #pragma unroll
      for (int n = 0; n < 4; n++)
        bf[n] = *(const bf16x8*)&Bc[(wn0 + n*16 + fr) * 64 + cs];
      #pragma unroll
      for (int m = 0; m < 4; m++)
        #pragma unroll
        for (int n = 0; n < 4; n++)
          acc[m][n] = __builtin_amdgcn_mfma_f32_16x16x32_bf16(af[m], bf[n], acc[m][n], 0, 0, 0);
    }
    __syncthreads();
  }

  // epilogue: C/D layout col = lane&15, row = (lane>>4)*4 + reg
  const int orow = (lane >> 4) * 4;
  const int ocol = lane & 15;
  #pragma unroll
  for (int n = 0; n < 4; n++) {
    const int col = bn0 + wn0 + n*16 + ocol;
    const float bv = bias ? bias[col] : 0.f;
    #pragma unroll
    for (int m = 0; m < 4; m++) {
      #pragma unroll
      for (int r = 0; r < 4; r++) {
        float v = acc[m][n][r] + bv;
        if (epi == 1) v = silu_f(v);
        else if (epi == 2) v = softplus_f(v);
        C[(size_t)(bm0 + wm0 + m*16 + orow + r) * Nn + col] = v;
      }
    }
  }
}

// fused in_proj + gate: grid (16,32); x<8 -> x1/no-act, x>=8 -> z/silu
__global__ __launch_bounds__(256) void gemm_ing_k(
    const short* __restrict__ ub,
    const short* __restrict__ Wti, const short* __restrict__ Wtg,
    const float* __restrict__ b_in, const float* __restrict__ bg,
    float* __restrict__ x1, float* __restrict__ z)
{
  __shared__ short As[2*128*64];
  __shared__ short Bs[2*128*64];
  int2 p = xcd_swz(gridDim.x);
  const int gate = p.x >> 3;
  gemm_core(ub, gate ? Wtg : Wti, gate ? bg : b_in, gate ? z : x1,
            DD, DD, 0, DD, p.y * 128, (p.x & 7) * 128, gate ? 1 : 0, As, Bs);
}

// out GEMM, split-K=2: grid (8,32,2). z picks K-half and partial buffer. Raw.
__global__ __launch_bounds__(256) void gemm_out_k(
    const short* __restrict__ xsb, const short* __restrict__ Wto,
    float* __restrict__ O0, float* __restrict__ O1)
{
  __shared__ short As[2*128*64];
  __shared__ short Bs[2*128*64];
  int2 p = xcd_swz(gridDim.x);
  const int s = blockIdx.z;
  gemm_core(xsb, Wto, nullptr, s ? O1 : O0,
            DD, DD, s * 512, 512, p.y * 128, p.x * 128, 0, As, Bs);
}

// ---------------------------------------------------------------------------
// Fused dt GEMM + B/C projections, split-K=2: grid (8,32,2) = 512 blocks
// (2 resident/CU). Raw partials: d{0,1}[M,D]; B{0,1}/C{0,1}[M,16].
// Bias + softplus fold into the scan kernels. BC tile: block covers rows
// [bm0+bx*16,+16) x 32 from already-staged A-frags + 4KB Wbct stage.
// ---------------------------------------------------------------------------
__global__ __launch_bounds__(256) void gemm_dtbc_k(
    const short* __restrict__ xb, const short* __restrict__ Wtd,
    const short* __restrict__ Wbct,
    float* __restrict__ d0, float* __restrict__ d1,
    float* __restrict__ B0, float* __restrict__ B1,
    float* __restrict__ C0, float* __restrict__ C1)
{
  __shared__ short As[2*128*64];
  __shared__ short Bs[2*128*64];
  __shared__ short Cs[2*32*64];
  int2 p = xcd_swz(gridDim.x);
  const int sp  = blockIdx.z;         // K-split half
  const int kB  = sp * 512;
  const int bx  = p.x;
  const int bm0 = p.y * 128;
  const int bn0 = bx * 128;
  float* dOut = sp ? d1 : d0;
  float* bOut = sp ? B1 : B0;
  float* cOut = sp ? C1 : C0;

  const int tid  = threadIdx.x;
  const int lane = tid & 63;
  const int w    = tid >> 6;
  const int wm0  = (w >> 1) * 64;
  const int wn0  = (w & 1) * 64;

  const int srow = tid >> 3;
  const int scol = ((tid & 7) ^ ((tid >> 3) & 7)) << 3;

  const short* gA = xb   + (size_t)(bm0 + srow) * DD + kB + scol;
  const short* gB = Wtd  + (size_t)(bn0 + srow) * DD + kB + scol;
  const short* gC = Wbct + (size_t)srow * DD + kB + scol;
  char* ldsA = (char*)As;
  char* ldsB = (char*)Bs;
  char* ldsC = (char*)Cs;
  const int wuni = w * 1024;

  f32x4 acc[4][4];
  const f32x4 zz = {0.f, 0.f, 0.f, 0.f};
  #pragma unroll
  for (int m = 0; m < 4; m++)
    #pragma unroll
    for (int n = 0; n < 4; n++) acc[m][n] = zz;
  f32x4 accbc = zz;

  const int fr  = lane & 15;
  const int ks  = (lane >> 4) << 3;
  const int swz = (fr & 7) << 3;

  // prologue
  #pragma unroll
  for (int i = 0; i < 4; i++) {
    gload16(gA + (size_t)(i * 32) * DD, ldsA + i * 4096 + wuni);
    gload16(gB + (size_t)(i * 32) * DD, ldsB + i * 4096 + wuni);
  }
  gload16(gC, ldsC + wuni);
  __syncthreads();

  for (int t = 0; t < 8; ++t) {
    const int cur = t & 1;
    if (t + 1 < 8) {
      const int k1 = (t + 1) << 6;
      const int bo = (cur ^ 1) * 16384;
      #pragma unroll
      for (int i = 0; i < 4; i++) {
        gload16(gA + (size_t)(i * 32) * DD + k1, ldsA + bo + i * 4096 + wuni);
        gload16(gB + (size_t)(i * 32) * DD + k1, ldsB + bo + i * 4096 + wuni);
      }
      gload16(gC + k1, ldsC + (cur ^ 1) * 4096 + wuni);
    }
    const short* Ac = As + cur * 8192;
    const short* Bc = Bs + cur * 8192;
    const short* Cc = Cs + cur * 2048;
    #pragma unroll
    for (int s = 0; s < 2; s++) {
      const int cs = ((s << 5) | ks) ^ swz;
      bf16x8 af[4], bf[4];
      #pragma unroll
      for (int m = 0; m < 4; m++)
        af[m] = *(const bf16x8*)&Ac[(wm0 + m*16 + fr) * 64 + cs];
      #pragma unroll
      for (int n = 0; n < 4; n++)
        bf[n] = *(const bf16x8*)&Bc[(wn0 + n*16 + fr) * 64 + cs];
      #pragma unroll
      for (int m = 0; m < 4; m++)
        #pragma unroll
        for (int n = 0; n < 4; n++)
          acc[m][n] = __builtin_amdgcn_mfma_f32_16x16x32_bf16(af[m], bf[n], acc[m][n], 0, 0, 0);
      if (w < 2) {
        bf16x8 abc = *(const bf16x8*)&Ac[(bx*16 + fr) * 64 + cs];
        bf16x8 bbc = *(const bf16x8*)&Cc[((w << 4) + fr) * 64 + cs];
        accbc = __builtin_amdgcn_mfma_f32_16x16x32_bf16(abc, bbc, accbc, 0, 0, 0);
      }
    }
    __syncthreads();
  }

  const int orow = (lane >> 4) * 4;
  const int ocol = lane & 15;
  #pragma unroll
  for (int n = 0; n < 4; n++) {
    const int col = bn0 + wn0 + n*16 + ocol;
    #pragma unroll
    for (int m = 0; m < 4; m++) {
      #pragma unroll
      for (int r = 0; r < 4; r++)
        dOut[(size_t)(bm0 + wm0 + m*16 + orow + r) * DD + col] = acc[m][n][r];
    }
  }
  if (w < 2) {
    float* dst = (w == 0) ? bOut : cOut;
    #pragma unroll
    for (int r = 0; r < 4; r++) {
      int row = bm0 + bx*16 + orow + r;
      dst[(size_t)row * NNs + ocol] = accbc[r];
    }
  }
}

// ---------------------------------------------------------------------------
// Depthwise conv3 (same over T) + silu -> bf16 xb only.
// ---------------------------------------------------------------------------
__global__ __launch_bounds__(256) void conv_silu(
    const float* __restrict__ x1, const float* __restrict__ cw,
    const float* __restrict__ cb, short* __restrict__ xb)
{
  int idx = blockIdx.x * 256 + threadIdx.x;       // over MM*DD/4
  int d4 = idx & (DD/4 - 1);
  int bt = idx >> 8;                              // DD/4 == 256
  int t  = bt & (TT - 1);
  const float4* b4 = (const float4*)x1;
  size_t ri = (size_t)bt * (DD/4) + d4;
  float4 zz = make_float4(0.f, 0.f, 0.f, 0.f);
  float4 vc = b4[ri];
  float4 vm = (t > 0)      ? b4[ri - DD/4] : zz;
  float4 vp = (t < TT - 1) ? b4[ri + DD/4] : zz;
  float rm[4] = {vm.x, vm.y, vm.z, vm.w};
  float rc[4] = {vc.x, vc.y, vc.z, vc.w};
  float rp[4] = {vp.x, vp.y, vp.z, vp.w};
  float o[4];
  #pragma unroll
  for (int j = 0; j < 4; j++) {
    int d = d4*4 + j;
    float v = rm[j]*cw[d*3+0] + rc[j]*cw[d*3+1] + rp[j]*cw[d*3+2] + cb[d];
    o[j] = silu_f(v);
  }
  ((uint2*)xb)[ri] = make_uint2(pk2(o[0], o[1]), pk2(o[2], o[3]));
}

// ---------------------------------------------------------------------------
// Selective scan, 3-phase chunked (32 chunks of 32; 512 blocks = 2 waves/SIMD)
// Phase 1 folds dt = softplus(d0+d1+bdt) ONCE and writes it back into d0
// (per-thread read-then-write, no hazard); scan_y reads the folded dt.
// 1-deep software prefetch hides strided-load latency under the exp/FMA chain.
// ---------------------------------------------------------------------------
__global__ __launch_bounds__(256) void scan_local(
    float* __restrict__ d0, const float* __restrict__ d1,
    const float* __restrict__ bdt, const short* __restrict__ xb,
    const float* __restrict__ B0, const float* __restrict__ B1,
    const float* __restrict__ bb, const float* __restrict__ A,
    float* __restrict__ P, float* __restrict__ S)
{
  __shared__ float Bsh[CHUNK*NNs];
  int bid = blockIdx.x;
  int dblk = bid & 3;
  int c = (bid >> 2) & (NCHUNK - 1);
  int b = bid >> 7;
  int d = dblk*256 + threadIdx.x;
  int t0 = c * CHUNK;
  size_t bo = (size_t)(b*TT + t0)*NNs;
  for (int i = threadIdx.x; i < CHUNK*NNs; i += 256)
    Bsh[i] = B0[bo + i] + B1[bo + i] + bb[i & 15];
  float a[NNs];
  #pragma unroll
  for (int n = 0; n < NNs; n++) a[n] = A[d*NNs + n];
  const float bdtv = bdt[d];
  __syncthreads();
  float h[NNs], p[NNs];
  #pragma unroll
  for (int n = 0; n < NNs; n++) { h[n] = 0.f; p[n] = 1.f; }
  size_t base = (size_t)(b*TT + t0)*DD + d;
  // software-pipelined loads (1 iter ahead)
  float pd0 = d0[base], pd1 = d1[base];
  short pxb = xb[base];
  for (int tt = 0; tt < CHUNK; tt++) {
    float cd0 = pd0, cd1 = pd1; short cxb = pxb;
    if (tt + 1 < CHUNK) {
      size_t gn = base + (size_t)(tt + 1)*DD;
      pd0 = d0[gn]; pd1 = d1[gn]; pxb = xb[gn];
    }
    float dtv = softplus_f(cd0 + cd1 + bdtv);
    d0[base + (size_t)tt*DD] = dtv;        // fold for scan_y
    float dx = dtv * bf2f(cxb);
    #pragma unroll
    for (int n = 0; n < NNs; n++) {
      float e = __expf(dtv * a[n]);
      h[n] = fmaf(e, h[n], dx * Bsh[tt*NNs + n]);
      p[n] *= e;
    }
  }
  size_t o = ((size_t)((b*NCHUNK + c)*DD + d)) * NNs;
  #pragma unroll
  for (int n = 0; n < NNs; n += 4) {
    *(float4*)&P[o+n] = make_float4(p[n], p[n+1], p[n+2], p[n+3]);
    *(float4*)&S[o+n] = make_float4(h[n], h[n+1], h[n+2], h[n+3]);
  }
}

__global__ __launch_bounds__(256) void scan_combine(
    const float* __restrict__ P, const float* __restrict__ S,
    float* __restrict__ H0)   // may alias P (read-before-write per idx)
{
  int g = blockIdx.x*256 + threadIdx.x;   // B*DD*NNs = 65536
  int n = g & 15; int d = (g >> 4) & 1023; int b = g >> 14;
  float h = 0.f;
  for (int c = 0; c < NCHUNK; c++) {
    size_t idx = ((size_t)((b*NCHUNK + c)*DD + d)) * NNs + n;
    float pv = P[idx], sv = S[idx];
    H0[idx] = h;
    h = fmaf(pv, h, sv);
  }
}

// Phase 3: replay with correct h0; y = <h,C>; fuse gate; write bf16 xsb
__global__ __launch_bounds__(256) void scan_y(
    const float* __restrict__ dtf, const short* __restrict__ xb,
    const float* __restrict__ B0, const float* __restrict__ B1,
    const float* __restrict__ bb,
    const float* __restrict__ C0, const float* __restrict__ C1,
    const float* __restrict__ bc,
    const float* __restrict__ A,  const float* __restrict__ H0,
    const float* __restrict__ z,  short* __restrict__ xsb)
{
  __shared__ float Bsh[CHUNK*NNs];
  __shared__ float Csh[CHUNK*NNs];
  int bid = blockIdx.x;
  int dblk = bid & 3;
  int c = (bid >> 2) & (NCHUNK - 1);
  int b = bid >> 7;
  int d = dblk*256 + threadIdx.x;
  int t0 = c * CHUNK;
  size_t bo = (size_t)(b*TT + t0)*NNs;
  for (int i = threadIdx.x; i < CHUNK*NNs; i += 256) {
    Bsh[i] = B0[bo + i] + B1[bo + i] + bb[i & 15];
    Csh[i] = C0[bo + i] + C1[bo + i] + bc[i & 15];
  }
  float a[NNs];
  #pragma unroll
  for (int n = 0; n < NNs; n++) a[n] = A[d*NNs + n];
  size_t ho = ((size_t)((b*NCHUNK + c)*DD + d)) * NNs;
  float h[NNs];
  #pragma unroll
  for (int n = 0; n < NNs; n += 4) {
    float4 h4 = *(const float4*)&H0[ho+n];
    h[n] = h4.x; h[n+1] = h4.y; h[n+2] = h4.z; h[n+3] = h4.w;
  }
  __syncthreads();
  size_t base = (size_t)(b*TT + t0)*DD + d;
  float pdt = dtf[base]; short pxb = xb[base]; float pz = z[base];
  for (int tt = 0; tt < CHUNK; tt++) {
    float cdt = pdt; short cxb = pxb; float cz = pz;
    if (tt + 1 < CHUNK) {
      size_t gn = base + (size_t)(tt + 1)*DD;
      pdt = dtf[gn]; pxb = xb[gn]; pz = z[gn];
    }
    float dx = cdt * bf2f(cxb);
    float y = 0.f;
    #pragma unroll
    for (int n = 0; n < NNs; n++) {
      float e = __expf(cdt * a[n]);
      h[n] = fmaf(e, h[n], dx * Bsh[tt*NNs + n]);
      y = fmaf(h[n], Csh[tt*NNs + n], y);
    }
    xsb[base + (size_t)tt*DD] = (short)f2bf(y * cz);
  }
}

// out = O0 + O1 + bout  (float4, 4 elems/thread)
__global__ __launch_bounds__(256) void out_epi(
    const float* __restrict__ O0, const float* __restrict__ O1,
    const float* __restrict__ bout, float* __restrict__ out)
{
  size_t i = (size_t)(blockIdx.x * 256 + threadIdx.x) * 4;
  int col = (int)(i & (DD - 1));
  float4 a = *(const float4*)(O0 + i);
  float4 b = *(const float4*)(O1 + i);
  float4 bv = *(const float4*)(bout + col);
  *(float4*)(out + i) = make_float4(a.x + b.x + bv.x, a.y + b.y + bv.y,
                                    a.z + b.z + bv.z, a.w + b.w + bv.w);
}

// ---------------------------------------------------------------------------
extern "C" void kernel_launch(void* const* d_in, const int* in_sizes, int n_in,
                              void* d_out, int out_size, void* d_ws, size_t ws_size,
                              hipStream_t stream)
{
  const float* u     = (const float*)d_in[0];
  const float* Win   = (const float*)d_in[1];
  const float* b_in  = (const float*)d_in[2];
  const float* Wg    = (const float*)d_in[3];
  const float* bg    = (const float*)d_in[4];
  const float* Wout  = (const float*)d_in[5];
  const float* bout  = (const float*)d_in[6];
  const float* convw = (const float*)d_in[7];
  const float* convb = (const float*)d_in[8];
  const float* A     = (const float*)d_in[9];
  const float* Wb    = (const float*)d_in[10];
  const float* bb    = (const float*)d_in[11];
  const float* Wc    = (const float*)d_in[12];
  const float* bc    = (const float*)d_in[13];
  const float* Wdt   = (const float*)d_in[14];
  const float* bdt   = (const float*)d_in[15];
  float* out = (float*)d_out;

  // workspace layout (~89 MB)
  float* ws = (float*)d_ws;
  float* x1 = ws;                         // [M,D] f32; P/S overlay later (16MB)
  float* z  = x1 + MMDD;                  // [M,D] f32 (gate, silu'd)
  float* d0 = z  + MMDD;                  // [M,D] f32 dt partial 0 -> folded dt
  float* d1 = d0 + MMDD;                  // [M,D] f32 dt partial 1; O1 overlays
  float* B0 = d1 + MMDD;                  // [M,16] x4 partials
  float* B1 = B0 + (size_t)MM*NNs;
  float* C0 = B1 + (size_t)MM*NNs;
  float* C1 = C0 + (size_t)MM*NNs;
  short* ub  = (short*)(C1 + (size_t)MM*NNs);  // [M,D] bf16
  short* xb  = ub  + MMDD;                // [M,D] bf16
  short* Wti = xb  + MMDD;                // [D,D] bf16 transposed x4
  short* Wtg = Wti + (size_t)DD*DD;
  short* Wtd = Wtg + (size_t)DD*DD;
  short* Wto = Wtd + (size_t)DD*DD;
  short* Wbct = Wto + (size_t)DD*DD;      // [32,D] bf16 (Wb^T | Wc^T)
  float* P  = x1;                         // 8MB, overlays x1 (dead after conv)
  float* S  = P + (size_t)BB*NCHUNK*DD*NNs;   // +8MB, still inside x1
  float* H0 = P;                          // combine is alias-safe (read first)
  float* O0 = d0;                         // out partials overlay d0/d1
  float* O1 = d1;
  short* xsb = ub;                        // reuse ub after in/gate GEMM

  // 0) weight prep + u->bf16
  wconv_t4<<<dim3(DD/32, DD/32, 4), 256, 0, stream>>>(
      Win, Wg, Wdt, Wout, Wti, Wtg, Wtd, Wto);
  wbc_t<<<(32*DD)/256, 256, 0, stream>>>(Wb, Wc, Wbct);
  to_bf16<<<(MMDD/8)/256, 256, 0, stream>>>(u, ub);

  // 1) fused in_proj (x1) + gate (z, silu)  [512 blocks = 2/CU]
  gemm_ing_k<<<dim3(16, MM/128), 256, 0, stream>>>(ub, Wti, Wtg, b_in, bg, x1, z);
  // 2) depthwise conv + silu -> xb (bf16)
  conv_silu<<<(MMDD/4)/256, 256, 0, stream>>>(x1, convw, convb, xb);
  // 3) dt partials + B/C partials, split-K=2 [512 blocks = 2/CU]
  gemm_dtbc_k<<<dim3(8, MM/128, 2), 256, 0, stream>>>(
      xb, Wtd, Wbct, d0, d1, B0, B1, C0, C1);
  // 4-6) chunked selective scan (folds partials+bias+softplus; writes dt->d0)
  scan_local  <<<BB*NCHUNK*(DD/256), 256, 0, stream>>>(
      d0, d1, bdt, xb, B0, B1, bb, A, P, S);
  scan_combine<<<(BB*DD*NNs)/256, 256, 0, stream>>>(P, S, H0);
  scan_y      <<<BB*NCHUNK*(DD/256), 256, 0, stream>>>(
      d0, xb, B0, B1, bb, C0, C1, bc, A, H0, z, xsb);
  // 7) out partials, split-K=2 [512 blocks = 2/CU]  (O0/O1 overlay d0/d1)
  gemm_out_k<<<dim3(8, MM/128, 2), 256, 0, stream>>>(xsb, Wto, O0, O1);
  // 8) out = O0 + O1 + bout
  out_epi<<<(MMDD/4)/256, 256, 0, stream>>>(O0, O1, bout, out);
}